// Round 1
// baseline (108.446 us; speedup 1.0000x reference)
//
#include <hip/hip_runtime.h>

// Chamfer distance on MI355X.
// B=4, N=8192 points per cloud, 3-D fp32.
// Strategy: brute-force O(N^2) pairwise min, fp32 VALU (no fp32 MFMA on CDNA4).
// Kernel 1: per-(dir,b,ptile,chunk) block computes per-p min over a q-chunk
//           staged in LDS (uniform broadcast reads).
// Kernel 2: per-batch reduction: min over chunks, mean over p, sum of both dirs.

#define N_PTS   8192
#define BATCH   4
#define QC      1024                 // q points per chunk
#define CHUNKS  (N_PTS / QC)         // 8
#define PTILE   256                  // p points per block (= blockDim.x)
#define PTILES  (N_PTS / PTILE)      // 32

__global__ __launch_bounds__(256) void chamfer_min_kernel(
    const float* __restrict__ pc1, const float* __restrict__ pc2,
    float* __restrict__ ws)
{
    int bid = blockIdx.x;
    const int chunk = bid & (CHUNKS - 1);  bid >>= 3;   // log2(CHUNKS)=3
    const int ptile = bid & (PTILES - 1);  bid >>= 5;   // log2(PTILES)=5
    const int b     = bid & (BATCH - 1);   bid >>= 2;   // log2(BATCH)=2
    const int dir   = bid;                               // 0: p from pc1, q from pc2

    const float* __restrict__ Aset = dir ? pc2 : pc1;   // "p" side
    const float* __restrict__ Bset = dir ? pc1 : pc2;   // "q" side

    // Stage the q-chunk into LDS: QC*3 floats = 12 KB, coalesced float4 loads.
    __shared__ float qs[QC * 3];
    {
        const float4* src = (const float4*)(Bset + ((size_t)b * N_PTS + (size_t)chunk * QC) * 3);
        float4* dst = (float4*)qs;
        for (int i = threadIdx.x; i < (QC * 3) / 4; i += PTILE)
            dst[i] = src[i];
    }
    __syncthreads();

    // Each thread owns one p point.
    const int p = ptile * PTILE + threadIdx.x;
    const float* pp = Aset + ((size_t)b * N_PTS + (size_t)p) * 3;
    const float px = pp[0], py = pp[1], pz = pp[2];

    // 4 independent min accumulators to break the dependency chain.
    float mm0 = 3.402823466e+38f, mm1 = 3.402823466e+38f;
    float mm2 = 3.402823466e+38f, mm3 = 3.402823466e+38f;

    #pragma unroll 4
    for (int q = 0; q < QC; q += 4) {
        const float* qp = &qs[3 * q];
        // q+0
        {
            const float dx = px - qp[0], dy = py - qp[1], dz = pz - qp[2];
            const float t = dx * dx + dy * dy + dz * dz;
            mm0 = fminf(mm0, t);
        }
        // q+1
        {
            const float dx = px - qp[3], dy = py - qp[4], dz = pz - qp[5];
            const float t = dx * dx + dy * dy + dz * dz;
            mm1 = fminf(mm1, t);
        }
        // q+2
        {
            const float dx = px - qp[6], dy = py - qp[7], dz = pz - qp[8];
            const float t = dx * dx + dy * dy + dz * dz;
            mm2 = fminf(mm2, t);
        }
        // q+3
        {
            const float dx = px - qp[9], dy = py - qp[10], dz = pz - qp[11];
            const float t = dx * dx + dy * dy + dz * dz;
            mm3 = fminf(mm3, t);
        }
    }

    const float m = fminf(fminf(mm0, mm1), fminf(mm2, mm3));
    // ws layout: [dir][b][p][chunk]
    ws[(((size_t)dir * BATCH + b) * N_PTS + p) * CHUNKS + chunk] = m;
}

__global__ __launch_bounds__(256) void chamfer_reduce_kernel(
    const float* __restrict__ ws, float* __restrict__ out)
{
    const int b = blockIdx.x;        // one block per batch
    float sum = 0.0f;

    for (int dir = 0; dir < 2; ++dir) {
        for (int p = threadIdx.x; p < N_PTS; p += 256) {
            const float* w = &ws[(((size_t)dir * BATCH + b) * N_PTS + p) * CHUNKS];
            float m = w[0];
            #pragma unroll
            for (int c = 1; c < CHUNKS; ++c) m = fminf(m, w[c]);
            sum += m;
        }
    }

    // Block reduction: wave64 shuffle, then cross-wave via LDS.
    for (int off = 32; off > 0; off >>= 1)
        sum += __shfl_down(sum, off, 64);

    __shared__ float red[4];
    const int wave = threadIdx.x >> 6;
    const int lane = threadIdx.x & 63;
    if (lane == 0) red[wave] = sum;
    __syncthreads();

    if (threadIdx.x == 0) {
        float tot = red[0] + red[1] + red[2] + red[3];
        out[b] = tot * (1.0f / (float)N_PTS);   // mean over p; both dirs share N=8192
    }
}

extern "C" void kernel_launch(void* const* d_in, const int* in_sizes, int n_in,
                              void* d_out, int out_size, void* d_ws, size_t ws_size,
                              hipStream_t stream)
{
    const float* pc1 = (const float*)d_in[0];
    const float* pc2 = (const float*)d_in[1];
    float* out = (float*)d_out;
    float* ws  = (float*)d_ws;   // needs 2*4*8192*8*4 B = 2 MiB

    const int nblocks = 2 * BATCH * PTILES * CHUNKS;   // 2048
    chamfer_min_kernel<<<nblocks, PTILE, 0, stream>>>(pc1, pc2, ws);
    chamfer_reduce_kernel<<<BATCH, 256, 0, stream>>>(ws, out);
}

// Round 2
// 50.780 us; speedup vs baseline: 2.1356x; 2.1356x over previous
//
#include <hip/hip_runtime.h>

// Chamfer distance, B=4, N=8192, fp32 3-D. Compute-bound fp32 VALU (no fp32 MFMA).
// Round 2: 4 VALU ops/pair via (-2q, ||q||^2) LDS precompute + ||p||^2 folded
// out of the min loop; 4 p-points per thread so one broadcast ds_read_b128
// feeds 16 VALU ops.

#define N_PTS   8192
#define BATCH   4
#define QC      512                     // q points per chunk
#define CHUNKS  (N_PTS / QC)            // 16
#define BLK     256
#define PT      4                       // p points per thread
#define P_PER_BLOCK (BLK * PT)          // 1024
#define PTILES  (N_PTS / P_PER_BLOCK)   // 8
#define RBLK    256
#define PBLKS   (N_PTS / RBLK)          // 32

__global__ __launch_bounds__(256) void chamfer_min_kernel(
    const float* __restrict__ pc1, const float* __restrict__ pc2,
    float* __restrict__ ws)
{
    int bid = blockIdx.x;
    const int chunk = bid & (CHUNKS - 1);  bid >>= 4;
    const int ptile = bid & (PTILES - 1);  bid >>= 3;
    const int b     = bid & (BATCH - 1);   bid >>= 2;
    const int dir   = bid;

    const float* __restrict__ A  = dir ? pc2 : pc1;   // "p" side
    const float* __restrict__ Bs = dir ? pc1 : pc2;   // "q" side

    // Stage+transform the q-chunk: (-2qx, -2qy, -2qz, ||q||^2), 16B-aligned.
    __shared__ float4 qs[QC];
    {
        const float* src = Bs + ((size_t)b * N_PTS + (size_t)chunk * QC) * 3;
        for (int i = threadIdx.x; i < QC; i += BLK) {
            const float qx = src[3*i], qy = src[3*i+1], qz = src[3*i+2];
            qs[i] = make_float4(-2.f*qx, -2.f*qy, -2.f*qz,
                                fmaf(qx, qx, fmaf(qy, qy, qz*qz)));
        }
    }
    __syncthreads();

    // Each thread owns 4 consecutive p points (48B contiguous -> 3 float4 loads).
    const int p0 = ptile * P_PER_BLOCK + threadIdx.x * PT;
    const float4* pp = (const float4*)(A + ((size_t)b * N_PTS + p0) * 3);
    const float4 v0 = pp[0], v1 = pp[1], v2 = pp[2];
    const float px[PT] = {v0.x, v0.w, v1.z, v2.y};
    const float py[PT] = {v0.y, v1.x, v1.w, v2.z};
    const float pz[PT] = {v0.z, v1.y, v2.x, v2.w};

    float mm[PT] = {3.402823466e+38f, 3.402823466e+38f,
                    3.402823466e+38f, 3.402823466e+38f};

    for (int q = 0; q < QC; q += 4) {
        #pragma unroll
        for (int u = 0; u < 4; ++u) {
            const float4 qv = qs[q + u];            // broadcast ds_read_b128
            #pragma unroll
            for (int i = 0; i < PT; ++i) {
                float acc = fmaf(pz[i], qv.z, qv.w);
                acc = fmaf(py[i], qv.y, acc);
                acc = fmaf(px[i], qv.x, acc);       // = ||q||^2 - 2 p.q
                mm[i] = fminf(mm[i], acc);
            }
        }
    }

    // Add ||p||^2 (hoisted out of the min) and store 4 consecutive floats.
    // ws layout: [dir][b][chunk][p] -> coalesced float4 store.
    float4 res;
    {
        float s;
        s = fmaf(px[0], px[0], fmaf(py[0], py[0], pz[0]*pz[0])); res.x = mm[0] + s;
        s = fmaf(px[1], px[1], fmaf(py[1], py[1], pz[1]*pz[1])); res.y = mm[1] + s;
        s = fmaf(px[2], px[2], fmaf(py[2], py[2], pz[2]*pz[2])); res.z = mm[2] + s;
        s = fmaf(px[3], px[3], fmaf(py[3], py[3], pz[3]*pz[3])); res.w = mm[3] + s;
    }
    float* wrow = ws + ((size_t)((dir * BATCH + b) * CHUNKS + chunk)) * N_PTS + p0;
    *(float4*)wrow = res;
}

// Stage 2a: per (dir,b,pblk of 256 p): min over chunks (coalesced), block-sum.
__global__ __launch_bounds__(256) void chamfer_reduce1(
    const float* __restrict__ ws, float* __restrict__ partial)
{
    int bid = blockIdx.x;
    const int pblk = bid & (PBLKS - 1); bid >>= 5;
    const int b    = bid & (BATCH - 1); bid >>= 2;
    const int dir  = bid;

    const int p = pblk * RBLK + threadIdx.x;
    const float* base = ws + ((size_t)(dir * BATCH + b)) * CHUNKS * N_PTS + p;
    float m = base[0];
    #pragma unroll
    for (int c = 1; c < CHUNKS; ++c) m = fminf(m, base[(size_t)c * N_PTS]);

    float s = m;
    for (int off = 32; off > 0; off >>= 1) s += __shfl_down(s, off, 64);

    __shared__ float red[4];
    if ((threadIdx.x & 63) == 0) red[threadIdx.x >> 6] = s;
    __syncthreads();
    if (threadIdx.x == 0)
        partial[(dir * BATCH + b) * PBLKS + pblk] = red[0] + red[1] + red[2] + red[3];
}

// Stage 2b: one block per batch; 64 threads read 2 dirs x 32 pblks.
__global__ __launch_bounds__(64) void chamfer_final(
    const float* __restrict__ partial, float* __restrict__ out)
{
    const int b = blockIdx.x;
    const int t = threadIdx.x;
    const int dir = t >> 5, k = t & 31;
    float v = partial[(dir * BATCH + b) * PBLKS + k];
    for (int off = 32; off > 0; off >>= 1) v += __shfl_down(v, off, 64);
    if (t == 0) out[b] = v * (1.0f / (float)N_PTS);
}

extern "C" void kernel_launch(void* const* d_in, const int* in_sizes, int n_in,
                              void* d_out, int out_size, void* d_ws, size_t ws_size,
                              hipStream_t stream)
{
    const float* pc1 = (const float*)d_in[0];
    const float* pc2 = (const float*)d_in[1];
    float* out = (float*)d_out;
    float* ws  = (float*)d_ws;                       // 4 MiB mins + 1 KiB partials
    float* partial = ws + (size_t)2 * BATCH * CHUNKS * N_PTS;

    const int nblocks = 2 * BATCH * PTILES * CHUNKS; // 1024
    chamfer_min_kernel<<<nblocks, BLK, 0, stream>>>(pc1, pc2, ws);
    chamfer_reduce1<<<2 * BATCH * PBLKS, RBLK, 0, stream>>>(ws, partial);
    chamfer_final<<<BATCH, 64, 0, stream>>>(partial, out);
}

// Round 3
// 42.427 us; speedup vs baseline: 2.5561x; 1.1969x over previous
//
#include <hip/hip_runtime.h>

// Chamfer distance, B=4, N=8192, fp32 3-D points, MI355X.
// Round 3: move the pairwise distance to the MFMA pipe.
//   dist(p,q) = sq1(p) + sq2(q) - 2 p.q, computed ENTIRELY inside one
//   v_mfma_f32_32x32x16_f16 via K-slot packing with f16 hi/lo splits:
//     s0-2 : hi_p * (-2 hi_q)    s3-5 : hi_p * (-2 lo_q)
//     s6-8 : lo_p * (-2 hi_q)    s9,10: sq1_hi,sq1_lo * 1
//     s11,12: 1 * sq2_hi,sq2_lo  s13-15: 0
//   (dropped lo_p*lo_q term ~2e-5 << 9.5e-4 threshold)
// One C pass serves BOTH directions: row-min -> d12, col-min -> d21.

typedef _Float16 half8  __attribute__((ext_vector_type(8)));
typedef float    f32x16 __attribute__((ext_vector_type(16)));

#define NPTS 8192
#define NB   4
#define QTILES_PER_B 256        // 8192 / 32
#define MAIN_TILES   128        // q-tiles per block (q-half)

// ---------- prepass: build B-side MFMA fragments (pc2 as Q) ----------
// wsB entry (tile*64 + lane) holds the half8 fragment lane `lane` needs.
// Assumed B layout: col = lane&31, k = (lane>>5)*8 + j  (any within-group
// k-permutation cancels because A is packed with the identical map).
__global__ __launch_bounds__(256) void chamfer_prep(
    const float* __restrict__ pc2, half8* __restrict__ wsB)
{
    const int tid  = blockIdx.x * 256 + threadIdx.x;   // 0..65535
    const int lane = tid & 63;
    const int tile = tid >> 6;                         // b*256 + t
    const int b    = tile >> 8;
    const int t    = tile & (QTILES_PER_B - 1);
    const int col  = lane & 31;
    const int g    = lane >> 5;

    const float* Q = pc2 + ((size_t)b * NPTS + t * 32 + col) * 3;
    const float qx = Q[0], qy = Q[1], qz = Q[2];

    const _Float16 hx = (_Float16)qx, hy = (_Float16)qy, hz = (_Float16)qz;
    const _Float16 lx = (_Float16)(qx - (float)hx);
    const _Float16 ly = (_Float16)(qy - (float)hy);
    const _Float16 lz = (_Float16)(qz - (float)hz);
    const float sq = fmaf(qx, qx, fmaf(qy, qy, qz * qz));
    const _Float16 sh = (_Float16)sq;
    const _Float16 sl = (_Float16)(sq - (float)sh);

    const _Float16 nhx = (_Float16)(-2.0f * (float)hx);  // exact (exp shift)
    const _Float16 nhy = (_Float16)(-2.0f * (float)hy);
    const _Float16 nhz = (_Float16)(-2.0f * (float)hz);
    const _Float16 nlx = (_Float16)(-2.0f * (float)lx);
    const _Float16 nly = (_Float16)(-2.0f * (float)ly);
    const _Float16 nlz = (_Float16)(-2.0f * (float)lz);
    const _Float16 one = (_Float16)1.0f, zz = (_Float16)0.0f;

    half8 v;
    if (g == 0) v = (half8){nhx, nhy, nhz, nlx, nly, nlz, nhx, nhy};
    else        v = (half8){nhz, one, one, sh,  sl,  zz,  zz,  zz};
    wsB[tid] = v;
}

// ---------- main: 256 blocks x 512 thr; block = (b, pstripe[256p], qhalf) ----
__global__ __launch_bounds__(512) void chamfer_main(
    const float* __restrict__ pc1, const half8* __restrict__ wsB,
    float* __restrict__ ws_col, float* __restrict__ ws_row)
{
    __shared__ unsigned colbuf[4096];   // per-q (local) encoded col-min

    const int tid = threadIdx.x;
    for (int i = tid; i < 4096; i += 512) colbuf[i] = 0xFFFFFFFFu;

    int bid = blockIdx.x;
    const int qh = bid & 1;  bid >>= 1;
    const int ps = bid & 31; bid >>= 5;
    const int b  = bid;

    const int w = tid >> 6, lane = tid & 63;
    const int col = lane & 31, g = lane >> 5;
    const int pbase = ps * 256 + w * 32;

    // Build the A fragment (pc1 as P), identical (g,j)->slot map as B.
    const float* P = pc1 + ((size_t)b * NPTS + pbase + col) * 3;
    const float px = P[0], py = P[1], pz = P[2];
    const _Float16 hx = (_Float16)px, hy = (_Float16)py, hz = (_Float16)pz;
    const _Float16 lx = (_Float16)(px - (float)hx);
    const _Float16 ly = (_Float16)(py - (float)hy);
    const _Float16 lz = (_Float16)(pz - (float)hz);
    const float sq1 = fmaf(px, px, fmaf(py, py, pz * pz));
    const _Float16 sh = (_Float16)sq1;
    const _Float16 sl = (_Float16)(sq1 - (float)sh);
    const _Float16 one = (_Float16)1.0f, zz = (_Float16)0.0f;

    half8 a;
    if (g == 0) a = (half8){hx, hy, hz, hx, hy, hz, lx, ly};
    else        a = (half8){lz, sh, sl, one, one, zz, zz, zz};

    __syncthreads();   // colbuf init visible

    const half8* Bbase = wsB + ((size_t)(b * QTILES_PER_B + qh * MAIN_TILES)) * 64 + lane;

    f32x16 rowmin;
    #pragma unroll
    for (int r = 0; r < 16; ++r) rowmin[r] = 3.402823466e+38f;
    f32x16 zero16 = {};

    half8 bf0 = Bbase[0];
    half8 bf1 = Bbase[64];

    for (int t = 0; t < MAIN_TILES; t += 2) {
        int t2 = t + 2, t3 = t + 3;
        if (t2 > MAIN_TILES - 1) t2 = MAIN_TILES - 1;
        if (t3 > MAIN_TILES - 1) t3 = MAIN_TILES - 1;
        const half8 n0 = Bbase[(size_t)t2 * 64];
        const half8 n1 = Bbase[(size_t)t3 * 64];

        #pragma unroll
        for (int u = 0; u < 2; ++u) {
            const half8 bf = u ? bf1 : bf0;
            const f32x16 acc = __builtin_amdgcn_mfma_f32_32x32x16_f16(a, bf, zero16, 0, 0, 0);
            rowmin = __builtin_elementwise_min(rowmin, acc);
            // col-min over this lane's 16 rows (tree, min3-fusable)
            float ma = fminf(fminf(acc[0], acc[1]), acc[2]);
            float mb = fminf(fminf(acc[3], acc[4]), acc[5]);
            float mc = fminf(fminf(acc[6], acc[7]), acc[8]);
            float md = fminf(fminf(acc[9], acc[10]), acc[11]);
            float me = fminf(fminf(acc[12], acc[13]), acc[14]);
            float m  = fminf(fminf(fminf(ma, mb), mc),
                             fminf(fminf(md, me), acc[15]));
            // monotone uint encoding, then LDS atomic min (both g halves hit
            // the same address -> 2-way, covers all 32 rows)
            const unsigned bits = __float_as_uint(m);
            const unsigned key  = bits ^ ((unsigned)((int)bits >> 31) | 0x80000000u);
            atomicMin(&colbuf[(t + u) * 32 + col], key);
        }
        bf0 = n0; bf1 = n1;
    }

    // row-min: butterfly across the 32 cols (bits 0..4), then col==0 lanes store
    #pragma unroll
    for (int r = 0; r < 16; ++r) {
        float v = rowmin[r];
        v = fminf(v, __shfl_xor(v, 1, 64));
        v = fminf(v, __shfl_xor(v, 2, 64));
        v = fminf(v, __shfl_xor(v, 4, 64));
        v = fminf(v, __shfl_xor(v, 8, 64));
        v = fminf(v, __shfl_xor(v, 16, 64));
        if (col == 0) {
            const int row = (r & 3) + 8 * (r >> 2) + 4 * g;   // m74/m101 C/D map
            ws_row[((size_t)(b * 2 + qh)) * NPTS + pbase + row] = v;
        }
    }

    __syncthreads();
    // decode + flush block's col-min partials
    for (int i = tid; i < 4096; i += 512) {
        const unsigned k = colbuf[i];
        const unsigned bits = k ^ ((unsigned)((int)~k >> 31) | 0x80000000u);
        ws_col[((size_t)(b * 32 + ps)) * NPTS + qh * 4096 + i] = __uint_as_float(bits);
    }
}

// ---------- reduce: min over partials, partial sums ----------
__global__ __launch_bounds__(256) void chamfer_reduce(
    const float* __restrict__ ws_col, const float* __restrict__ ws_row,
    float* __restrict__ partial)
{
    const int bid = blockIdx.x;          // 4b x 32 slices
    const int s = bid & 31, b = bid >> 5;
    const int i = s * 256 + threadIdx.x;

    float m = ws_col[((size_t)(b * 32)) * NPTS + i];
    #pragma unroll 4
    for (int ps = 1; ps < 32; ++ps)
        m = fminf(m, ws_col[((size_t)(b * 32 + ps)) * NPTS + i]);
    float sum = m;
    sum += fminf(ws_row[((size_t)(b * 2)) * NPTS + i],
                 ws_row[((size_t)(b * 2 + 1)) * NPTS + i]);

    for (int off = 32; off; off >>= 1) sum += __shfl_down(sum, off, 64);
    __shared__ float red[4];
    if (!(threadIdx.x & 63)) red[threadIdx.x >> 6] = sum;
    __syncthreads();
    if (!threadIdx.x) partial[bid] = red[0] + red[1] + red[2] + red[3];
}

__global__ __launch_bounds__(64) void chamfer_final(
    const float* __restrict__ partial, float* __restrict__ out)
{
    const int b = blockIdx.x, t = threadIdx.x;
    float v = (t < 32) ? partial[b * 32 + t] : 0.0f;
    for (int off = 32; off; off >>= 1) v += __shfl_down(v, off, 64);
    if (!t) out[b] = v * (1.0f / (float)NPTS);
}

extern "C" void kernel_launch(void* const* d_in, const int* in_sizes, int n_in,
                              void* d_out, int out_size, void* d_ws, size_t ws_size,
                              hipStream_t stream)
{
    const float* pc1 = (const float*)d_in[0];
    const float* pc2 = (const float*)d_in[1];
    float* out = (float*)d_out;

    char* ws = (char*)d_ws;
    half8* wsB     = (half8*)ws;                                  // 1 MiB
    float* ws_col  = (float*)(ws + (1 << 20));                    // 4 MiB
    float* ws_row  = (float*)(ws + (5 << 20));                    // 256 KiB
    float* partial = (float*)(ws + (5 << 20) + (256 << 10));      // 512 B

    chamfer_prep<<<256, 256, 0, stream>>>(pc2, wsB);
    chamfer_main<<<256, 512, 0, stream>>>(pc1, wsB, ws_col, ws_row);
    chamfer_reduce<<<128, 256, 0, stream>>>(ws_col, ws_row, partial);
    chamfer_final<<<NB, 64, 0, stream>>>(partial, out);
}

// Round 4
// 39.760 us; speedup vs baseline: 2.7275x; 1.0671x over previous
//
#include <hip/hip_runtime.h>

// Chamfer distance, B=4, N=8192, fp32 3-D points, MI355X.
// Round 4: same MFMA K-slot algorithm as round 3 (verified correct), now
// tuned for issue efficiency:
//  - grid 512 (2 blocks/CU, 4 waves/SIMD) via 4-way q-split
//  - raw-bits LDS atomicMin (distances >= 0 up to ~1e-5 fp error << 9.5e-4)
//  - rowmin folded over tile pairs (min3-fusable), colmin tree in triples

typedef _Float16 half8  __attribute__((ext_vector_type(8)));
typedef float    f32x16 __attribute__((ext_vector_type(16)));

#define NPTS 8192
#define NB   4
#define QTILES_PER_B 256        // 8192 / 32
#define TPB  64                 // q-tiles per block (q-quarter)

// ---------- prepass: build B-side MFMA fragments (pc2 as Q) ----------
__global__ __launch_bounds__(256) void chamfer_prep(
    const float* __restrict__ pc2, half8* __restrict__ wsB)
{
    const int tid  = blockIdx.x * 256 + threadIdx.x;   // 0..65535
    const int lane = tid & 63;
    const int tile = tid >> 6;                         // b*256 + t
    const int b    = tile >> 8;
    const int t    = tile & (QTILES_PER_B - 1);
    const int col  = lane & 31;
    const int g    = lane >> 5;

    const float* Q = pc2 + ((size_t)b * NPTS + t * 32 + col) * 3;
    const float qx = Q[0], qy = Q[1], qz = Q[2];

    const _Float16 hx = (_Float16)qx, hy = (_Float16)qy, hz = (_Float16)qz;
    const _Float16 lx = (_Float16)(qx - (float)hx);
    const _Float16 ly = (_Float16)(qy - (float)hy);
    const _Float16 lz = (_Float16)(qz - (float)hz);
    const float sq = fmaf(qx, qx, fmaf(qy, qy, qz * qz));
    const _Float16 sh = (_Float16)sq;
    const _Float16 sl = (_Float16)(sq - (float)sh);

    const _Float16 nhx = (_Float16)(-2.0f * (float)hx);
    const _Float16 nhy = (_Float16)(-2.0f * (float)hy);
    const _Float16 nhz = (_Float16)(-2.0f * (float)hz);
    const _Float16 nlx = (_Float16)(-2.0f * (float)lx);
    const _Float16 nly = (_Float16)(-2.0f * (float)ly);
    const _Float16 nlz = (_Float16)(-2.0f * (float)lz);
    const _Float16 one = (_Float16)1.0f, zz = (_Float16)0.0f;

    half8 v;
    if (g == 0) v = (half8){nhx, nhy, nhz, nlx, nly, nlz, nhx, nhy};
    else        v = (half8){nhz, one, one, sh,  sl,  zz,  zz,  zz};
    wsB[tid] = v;
}

// ---------- main: 512 blocks x 512 thr; block = (b, pstripe[256p], qquarter) --
__global__ __launch_bounds__(512, 4) void chamfer_main(
    const float* __restrict__ pc1, const half8* __restrict__ wsB,
    float* __restrict__ ws_col, float* __restrict__ ws_row)
{
    __shared__ unsigned colbuf[2048];   // per-q (local) col-min, raw f32 bits

    const int tid = threadIdx.x;
    for (int i = tid; i < 2048; i += 512) colbuf[i] = 0xFFFFFFFFu;

    int bid = blockIdx.x;
    const int qq = bid & 3;  bid >>= 2;
    const int ps = bid & 31; bid >>= 5;
    const int b  = bid;

    const int w = tid >> 6, lane = tid & 63;
    const int col = lane & 31, g = lane >> 5;
    const int pbase = ps * 256 + w * 32;

    // A fragment (pc1 as P), identical (g,j)->K-slot map as B.
    const float* P = pc1 + ((size_t)b * NPTS + pbase + col) * 3;
    const float px = P[0], py = P[1], pz = P[2];
    const _Float16 hx = (_Float16)px, hy = (_Float16)py, hz = (_Float16)pz;
    const _Float16 lx = (_Float16)(px - (float)hx);
    const _Float16 ly = (_Float16)(py - (float)hy);
    const _Float16 lz = (_Float16)(pz - (float)hz);
    const float sq1 = fmaf(px, px, fmaf(py, py, pz * pz));
    const _Float16 sh = (_Float16)sq1;
    const _Float16 sl = (_Float16)(sq1 - (float)sh);
    const _Float16 one = (_Float16)1.0f, zz = (_Float16)0.0f;

    half8 a;
    if (g == 0) a = (half8){hx, hy, hz, hx, hy, hz, lx, ly};
    else        a = (half8){lz, sh, sl, one, one, zz, zz, zz};

    __syncthreads();   // colbuf init visible

    const half8* Bbase = wsB + ((size_t)(b * QTILES_PER_B + qq * TPB)) * 64 + lane;

    f32x16 rowmin;
    #pragma unroll
    for (int r = 0; r < 16; ++r) rowmin[r] = 3.402823466e+38f;
    const f32x16 zero16 = {};

    half8 bf0 = Bbase[0];
    half8 bf1 = Bbase[64];

    for (int t = 0; t < TPB; t += 2) {
        const int t2 = (t + 2 < TPB) ? t + 2 : TPB - 1;
        const int t3 = (t + 3 < TPB) ? t + 3 : TPB - 1;
        const half8 n0 = Bbase[(size_t)t2 * 64];
        const half8 n1 = Bbase[(size_t)t3 * 64];

        const f32x16 acc0 = __builtin_amdgcn_mfma_f32_32x32x16_f16(a, bf0, zero16, 0, 0, 0);
        const f32x16 acc1 = __builtin_amdgcn_mfma_f32_32x32x16_f16(a, bf1, zero16, 0, 0, 0);

        // col-min for each tile (min3-shaped tree), raw-bits LDS atomicMin
        {
            float ma = fminf(fminf(acc0[0], acc0[1]), acc0[2]);
            float mb = fminf(fminf(acc0[3], acc0[4]), acc0[5]);
            float mc = fminf(fminf(acc0[6], acc0[7]), acc0[8]);
            float md = fminf(fminf(acc0[9], acc0[10]), acc0[11]);
            float me = fminf(fminf(acc0[12], acc0[13]), acc0[14]);
            float m  = fminf(fminf(fminf(ma, mb), mc),
                             fminf(fminf(md, me), acc0[15]));
            atomicMin(&colbuf[t * 32 + col], __float_as_uint(m));
        }
        {
            float ma = fminf(fminf(acc1[0], acc1[1]), acc1[2]);
            float mb = fminf(fminf(acc1[3], acc1[4]), acc1[5]);
            float mc = fminf(fminf(acc1[6], acc1[7]), acc1[8]);
            float md = fminf(fminf(acc1[9], acc1[10]), acc1[11]);
            float me = fminf(fminf(acc1[12], acc1[13]), acc1[14]);
            float m  = fminf(fminf(fminf(ma, mb), mc),
                             fminf(fminf(md, me), acc1[15]));
            atomicMin(&colbuf[(t + 1) * 32 + col], __float_as_uint(m));
        }

        // row-min folded over the tile pair (min3-fusable per element)
        #pragma unroll
        for (int r = 0; r < 16; ++r)
            rowmin[r] = fminf(rowmin[r], fminf(acc0[r], acc1[r]));

        bf0 = n0; bf1 = n1;
    }

    // row-min across the 32 cols, col==0 lanes store
    #pragma unroll
    for (int r = 0; r < 16; ++r) {
        float v = rowmin[r];
        v = fminf(v, __shfl_xor(v, 1, 64));
        v = fminf(v, __shfl_xor(v, 2, 64));
        v = fminf(v, __shfl_xor(v, 4, 64));
        v = fminf(v, __shfl_xor(v, 8, 64));
        v = fminf(v, __shfl_xor(v, 16, 64));
        if (col == 0) {
            const int row = (r & 3) + 8 * (r >> 2) + 4 * g;   // m74/m101 C/D map
            ws_row[((size_t)(b * 4 + qq)) * NPTS + pbase + row] = v;
        }
    }

    __syncthreads();
    // flush block's col-min partials (raw bits ARE the float)
    for (int i = tid; i < 2048; i += 512)
        ws_col[((size_t)(b * 32 + ps)) * NPTS + qq * 2048 + i] =
            __uint_as_float(colbuf[i]);
}

// ---------- reduce: min over partials, partial sums ----------
__global__ __launch_bounds__(256) void chamfer_reduce(
    const float* __restrict__ ws_col, const float* __restrict__ ws_row,
    float* __restrict__ partial)
{
    const int bid = blockIdx.x;          // 4b x 32 slices
    const int s = bid & 31, b = bid >> 5;
    const int i = s * 256 + threadIdx.x;

    float m = ws_col[((size_t)(b * 32)) * NPTS + i];
    #pragma unroll 4
    for (int ps = 1; ps < 32; ++ps)
        m = fminf(m, ws_col[((size_t)(b * 32 + ps)) * NPTS + i]);

    float r0 = ws_row[((size_t)(b * 4 + 0)) * NPTS + i];
    float r1 = ws_row[((size_t)(b * 4 + 1)) * NPTS + i];
    float r2 = ws_row[((size_t)(b * 4 + 2)) * NPTS + i];
    float r3 = ws_row[((size_t)(b * 4 + 3)) * NPTS + i];
    float sum = m + fminf(fminf(r0, r1), fminf(r2, r3));

    for (int off = 32; off; off >>= 1) sum += __shfl_down(sum, off, 64);
    __shared__ float red[4];
    if (!(threadIdx.x & 63)) red[threadIdx.x >> 6] = sum;
    __syncthreads();
    if (!threadIdx.x) partial[bid] = red[0] + red[1] + red[2] + red[3];
}

__global__ __launch_bounds__(64) void chamfer_final(
    const float* __restrict__ partial, float* __restrict__ out)
{
    const int b = blockIdx.x, t = threadIdx.x;
    float v = (t < 32) ? partial[b * 32 + t] : 0.0f;
    for (int off = 32; off; off >>= 1) v += __shfl_down(v, off, 64);
    if (!t) out[b] = v * (1.0f / (float)NPTS);
}

extern "C" void kernel_launch(void* const* d_in, const int* in_sizes, int n_in,
                              void* d_out, int out_size, void* d_ws, size_t ws_size,
                              hipStream_t stream)
{
    const float* pc1 = (const float*)d_in[0];
    const float* pc2 = (const float*)d_in[1];
    float* out = (float*)d_out;

    char* ws = (char*)d_ws;
    half8* wsB     = (half8*)ws;                                  // 1 MiB
    float* ws_col  = (float*)(ws + (1 << 20));                    // 4 MiB
    float* ws_row  = (float*)(ws + (5 << 20));                    // 512 KiB
    float* partial = (float*)(ws + (5 << 20) + (512 << 10));      // 512 B

    chamfer_prep<<<256, 256, 0, stream>>>(pc2, wsB);
    chamfer_main<<<512, 512, 0, stream>>>(pc1, wsB, ws_col, ws_row);
    chamfer_reduce<<<128, 256, 0, stream>>>(ws_col, ws_row, partial);
    chamfer_final<<<NB, 64, 0, stream>>>(partial, out);
}